// Round 17
// baseline (68.737 us; speedup 1.0000x reference)
//
#include <hip/hip_runtime.h>
#include <hip/hip_bf16.h>

#define H_IN 4096
#define W_IN 4096
#define KH 15
#define KW 15
#define OH (H_IN - KH + 1)   // 4082
#define OW (W_IN - KW + 1)   // 4082

#define BM 64                // output rows per tile (4 waves x 16)
#define BN 128               // output cols per tile (NJ=8 j-frags)
#define NJ (BN / 16)         // 8
#define SROWS (BM + KH - 1)  // 78 staged rows
#define SCOLS 144            // staged bf16 cols (128 + 16 k-window)
#define SSTR  152            // LDS row stride in ushort = 19 granules; compact
                             // (capacity > conflicts, r14; ~17% LDS tax accepted)
#define SCH4 36              // float4 chunks per staged row
#define STAGE_N (SROWS * SCH4)   // 2808
#define NLOAD 11             // ceil(STAGE_N / 256)
#define TPB 4                // y-tiles per block, software-pipelined

typedef __attribute__((ext_vector_type(8))) short short8;   // MFMA A/B frag
typedef __attribute__((ext_vector_type(4))) float f32x4;    // MFMA C/D frag

__device__ __forceinline__ ushort f2bf(float f) {
    __hip_bfloat16 h = __float2bfloat16(f);       // native v_cvt path
    return __builtin_bit_cast(ushort, h);
}

// ---- prep: banded Toeplitz weight frags -> workspace (15 KB) ----
// B[k][j] = w[kh][k-j]; frag: lane l holds B[8*(l>>4)+u][l&15], u=0..7
__global__ __launch_bounds__(256)
void build_wfrags(const float* __restrict__ Wt, ushort* __restrict__ Bw)
{
    int idx = blockIdx.x * 256 + threadIdx.x;
    if (idx < KH * 64) {
        int kh = idx >> 6, l = idx & 63;
        int j = l & 15, k0 = (l >> 4) * 8;
        union { ushort u[8]; uint4 v; } t;
#pragma unroll
        for (int u = 0; u < 8; ++u) {
            int kw = k0 + u - j;
            t.u[u] = f2bf((kw >= 0 && kw < KW) ? Wt[kh * KW + kw] : 0.0f);
        }
        *reinterpret_cast<uint4*>(&Bw[idx * 8]) = t.v;
    }
}

__device__ __forceinline__ void stage_issue(const float* __restrict__ X,
                                            int iy0, int ox0, bool xint,
                                            int tid, float4 (&v)[NLOAD])
{
#pragma unroll
    for (int k = 0; k < NLOAD; ++k) {
        int i = tid + 256 * k;
        if (i < STAGE_N) {
            int r  = i / SCH4;
            int c4 = i % SCH4;
            int gy = min(iy0 + r, H_IN - 1);
            const float* rp = X + (size_t)gy * W_IN;
            int gx = ox0 + c4 * 4;
            if (xint) {
                v[k] = *reinterpret_cast<const float4*>(rp + gx);
            } else {
                v[k].x = rp[min(gx + 0, W_IN - 1)];
                v[k].y = rp[min(gx + 1, W_IN - 1)];
                v[k].z = rp[min(gx + 2, W_IN - 1)];
                v[k].w = rp[min(gx + 3, W_IN - 1)];
            }
        }
    }
}

__device__ __forceinline__ void stage_write(ushort* __restrict__ s_x,
                                            int tid, const float4 (&v)[NLOAD])
{
#pragma unroll
    for (int k = 0; k < NLOAD; ++k) {
        int i = tid + 256 * k;
        if (i < STAGE_N) {
            int r  = i / SCH4;
            int c4 = i % SCH4;
            uint2 pk;
            pk.x = (uint32_t)f2bf(v[k].x) | ((uint32_t)f2bf(v[k].y) << 16);
            pk.y = (uint32_t)f2bf(v[k].z) | ((uint32_t)f2bf(v[k].w) << 16);
            *reinterpret_cast<uint2*>(&s_x[r * SSTR + c4 * 4]) = pk;
        }
    }
}

__global__ __launch_bounds__(256, 2)   // VGPR cap 256: bfr+v+acc all stay live
void conv2d_mfma_deep(const float* __restrict__ X,
                      const ushort* __restrict__ Bw,
                      const float* __restrict__ Bias,
                      float* __restrict__ Out)
{
    __shared__ ushort s_x[SROWS * SSTR];     // 23712 B, single buffer

    const int tid = threadIdx.x;
    const int l = tid & 63;
    const int w = tid >> 6;
    const int ox0 = blockIdx.x * BN;
    const int ty0 = blockIdx.y * TPB;
    const bool xint = (ox0 + SCOLS <= W_IN);
    const float b = Bias[0];

    float4 v[NLOAD];

    // ---- prologue: issue tile-0 loads FIRST (HBM latency), then B hoist ----
    stage_issue(X, ty0 * BM, ox0, xint, tid, v);

    const ushort* const bbase = Bw + l * 8;
    short8 bfr[KH];                          // 60 VGPR, fits under cap 256
#pragma unroll
    for (int kh = 0; kh < KH; ++kh)
        bfr[kh] = *reinterpret_cast<const short8*>(bbase + kh * 64 * 8);
    __builtin_amdgcn_sched_barrier(0);       // pin hoist before everything else

    stage_write(s_x, tid, v);
    __syncthreads();

    const ushort* const abase = &s_x[(w * 16 + (l & 15)) * SSTR + (l >> 4) * 8];

#pragma unroll
    for (int t = 0; t < TPB; ++t) {
        const int oy0 = (ty0 + t) * BM;

        // ---- prefetch next tile: kh loop has ZERO vmem, loads fly through ----
        if (t + 1 < TPB)
            stage_issue(X, (ty0 + t + 1) * BM, ox0, xint, tid, v);
        __builtin_amdgcn_sched_barrier(0);

        // ---- compute: per kh {8 LDS A-reads, 8 MFMAs}, B in registers ----
        f32x4 acc[NJ];
#pragma unroll
        for (int j = 0; j < NJ; ++j) acc[j] = (f32x4){0.f, 0.f, 0.f, 0.f};

#pragma unroll
        for (int kh = 0; kh < KH; ++kh) {
            const ushort* arow = abase + kh * SSTR;
#pragma unroll
            for (int j = 0; j < NJ; ++j) {
                short8 a = *reinterpret_cast<const short8*>(arow + j * 16);
                acc[j] = __builtin_amdgcn_mfma_f32_16x16x32_bf16(a, bfr[kh], acc[j], 0, 0, 0);
            }
        }

        // ---- store: C/D layout col=lane&15, row=(lane>>4)*4+r ----
        const int orow0 = oy0 + w * 16 + (l >> 4) * 4;
        const int ocol  = ox0 + (l & 15);
        if (oy0 + BM <= OH && ox0 + BN <= OW) {
            float* op0 = &Out[(size_t)orow0 * OW + ocol];
#pragma unroll
            for (int j = 0; j < NJ; ++j) {
#pragma unroll
                for (int r = 0; r < 4; ++r)
                    op0[(size_t)r * OW + j * 16] = acc[j][r] + b;
            }
        } else {
#pragma unroll
            for (int j = 0; j < NJ; ++j) {
                int oc = ocol + j * 16;
                if (oc < OW) {
#pragma unroll
                    for (int r = 0; r < 4; ++r) {
                        int orow = orow0 + r;
                        if (orow < OH)
                            Out[(size_t)orow * OW + oc] = acc[j][r] + b;
                    }
                }
            }
        }

        // ---- handoff: drain readers, publish tile t+1 ----
        if (t + 1 < TPB) {
            __syncthreads();            // all waves done reading tile t
            stage_write(s_x, tid, v);
            __syncthreads();            // tile t+1 visible
        }
    }
}

extern "C" void kernel_launch(void* const* d_in, const int* in_sizes, int n_in,
                              void* d_out, int out_size, void* d_ws, size_t ws_size,
                              hipStream_t stream)
{
    const float* X    = (const float*)d_in[0];
    const float* Wt   = (const float*)d_in[1];
    const float* Bias = (const float*)d_in[2];
    float* Out        = (float*)d_out;
    ushort* Bw        = (ushort*)d_ws;        // 15*64*8 ushort = 15360 B

    hipLaunchKernelGGL(build_wfrags, dim3((KH * 64 + 255) / 256), dim3(256), 0, stream,
                       Wt, Bw);

    dim3 grid((OW + BN - 1) / BN,                // 32
              (OH + BM * TPB - 1) / (BM * TPB)); // 16 -> 512 blocks = 2/CU exact
    dim3 block(256);
    hipLaunchKernelGGL(conv2d_mfma_deep, grid, block, 0, stream, X, Bw, Bias, Out);
}

// Round 18
// 44.823 us; speedup vs baseline: 1.5335x; 1.5335x over previous
//
#include <hip/hip_runtime.h>
#include <hip/hip_bf16.h>

#define H_IN 4096
#define W_IN 4096
#define KH 15
#define KW 15
#define OH (H_IN - KH + 1)   // 4082
#define OW (W_IN - KW + 1)   // 4082

#define BM 64                // output rows per block (4 waves x 16)
#define BN 128               // output cols per block (NJ=8 j-frags)
#define NJ (BN / 16)         // 8
#define SROWS (BM + KH - 1)  // 78 staged rows
#define SCOLS 144            // staged bf16 cols (128 + 16 k-window)
#define SSTR  152            // LDS row stride in ushort = 19 granules (19%8==3)
#define SCH4 36              // float4 chunks per staged row
#define STAGE_N (SROWS * SCH4)   // 2808 items
#define NLOAD 11             // ceil(STAGE_N / 256)

typedef __attribute__((ext_vector_type(8))) short short8;   // MFMA A/B frag
typedef __attribute__((ext_vector_type(4))) float f32x4;    // MFMA C/D frag

__device__ __forceinline__ ushort f2bf(float f) {
    __hip_bfloat16 h = __float2bfloat16(f);       // native v_cvt path
    return __builtin_bit_cast(ushort, h);
}

// ---- prep: build banded Toeplitz weight frags into workspace (15 KB) ----
// B[k][j] = w[kh][k-j]; frag layout: lane l holds B[8*(l>>4)+u][l&15], u=0..7
__global__ __launch_bounds__(256)
void build_wfrags(const float* __restrict__ Wt, ushort* __restrict__ Bw)
{
    int idx = blockIdx.x * 256 + threadIdx.x;    // frag-lane index
    if (idx < KH * 64) {
        int kh = idx >> 6, l = idx & 63;
        int j = l & 15, k0 = (l >> 4) * 8;
        union { ushort u[8]; uint4 v; } t;
#pragma unroll
        for (int u = 0; u < 8; ++u) {
            int kw = k0 + u - j;
            t.u[u] = f2bf((kw >= 0 && kw < KW) ? Wt[kh * KW + kw] : 0.0f);
        }
        *reinterpret_cast<uint4*>(&Bw[idx * 8]) = t.v;   // single 16B store
    }
}

__global__ __launch_bounds__(256, 4)
void conv2d_mfma_bf16(const float* __restrict__ X,
                      const ushort* __restrict__ Bw,
                      const float* __restrict__ Bias,
                      float* __restrict__ Out)
{
    __shared__ ushort s_x[SROWS * SSTR];     // 23712 B — tile only

    // ---- convoy breaker: stagger co-resident dispatch batches.
    // Co-resident blocks on a CU are bid, bid+256, ... (round-robin dispatch).
    // Batch k (k<6) sleeps ~k*1.7k cycles once; afterwards the ~6 resident
    // blocks per CU sit ~1/6 period apart (stage of one overlaps compute of
    // others), and successors inherit the offset. s_sleep burns no pipes.
    {
        const int bid = blockIdx.y * gridDim.x + blockIdx.x;
        const int batch = bid >> 8;              // dispatch batch index
        const int phase = (batch < 6) ? batch : 0;
        for (int i = 0; i < phase; ++i)
            __builtin_amdgcn_s_sleep(27);        // ~1.7k cycles per step
    }

    const int tid = threadIdx.x;
    const int l = tid & 63;
    const int w = tid >> 6;
    const int ox0 = blockIdx.x * BN;
    const int oy0 = blockIdx.y * BM;
    const bool xint = (ox0 + SCOLS <= W_IN);

    // ---- stage phase A: issue ALL tile loads (one vmcnt drain, T14 split) ----
    float4 v[NLOAD];
#pragma unroll
    for (int k = 0; k < NLOAD; ++k) {
        int i = tid + 256 * k;
        if (i < STAGE_N) {
            int r  = i / SCH4;
            int c4 = i % SCH4;
            int gy = min(oy0 + r, H_IN - 1);
            const float* rp = X + (size_t)gy * W_IN;
            int gx = ox0 + c4 * 4;
            if (xint) {
                v[k] = *reinterpret_cast<const float4*>(rp + gx);
            } else {
                v[k].x = rp[min(gx + 0, W_IN - 1)];
                v[k].y = rp[min(gx + 1, W_IN - 1)];
                v[k].z = rp[min(gx + 2, W_IN - 1)];
                v[k].w = rp[min(gx + 3, W_IN - 1)];
            }
        }
    }
    // ---- stage phase B: convert + LDS write ----
#pragma unroll
    for (int k = 0; k < NLOAD; ++k) {
        int i = tid + 256 * k;
        if (i < STAGE_N) {
            int r  = i / SCH4;
            int c4 = i % SCH4;
            uint2 pk;
            pk.x = (uint32_t)f2bf(v[k].x) | ((uint32_t)f2bf(v[k].y) << 16);
            pk.y = (uint32_t)f2bf(v[k].z) | ((uint32_t)f2bf(v[k].w) << 16);
            *reinterpret_cast<uint2*>(&s_x[r * SSTR + c4 * 4]) = pk;
        }
    }
    __syncthreads();       // only barrier in the kernel

    // ---- B-frags: L1-hot global loads (compiler chooses placement) ----
    const ushort* const bbase = Bw + l * 8;
    short8 bfr[KH];
#pragma unroll
    for (int kh = 0; kh < KH; ++kh)
        bfr[kh] = *reinterpret_cast<const short8*>(bbase + kh * 64 * 8);
    __builtin_amdgcn_sched_barrier(0);

    // ---- compute: per kh {8 A-reads, 8 MFMAs} ----
    const ushort* const abase = &s_x[(w * 16 + (l & 15)) * SSTR + (l >> 4) * 8];

    f32x4 acc[NJ];
#pragma unroll
    for (int j = 0; j < NJ; ++j) acc[j] = (f32x4){0.f, 0.f, 0.f, 0.f};

#pragma unroll
    for (int kh = 0; kh < KH; ++kh) {
        const ushort* arow = abase + kh * SSTR;
#pragma unroll
        for (int j = 0; j < NJ; ++j) {
            short8 a = *reinterpret_cast<const short8*>(arow + j * 16);
            acc[j] = __builtin_amdgcn_mfma_f32_16x16x32_bf16(a, bfr[kh], acc[j], 0, 0, 0);
        }
    }

    // ---- store: C/D layout col=lane&15, row=(lane>>4)*4+r ----
    const float b = Bias[0];
    const int orow0 = oy0 + w * 16 + (l >> 4) * 4;
    const int ocol  = ox0 + (l & 15);
    if (oy0 + BM <= OH && ox0 + BN <= OW) {
        float* op0 = &Out[(size_t)orow0 * OW + ocol];
#pragma unroll
        for (int j = 0; j < NJ; ++j) {
#pragma unroll
            for (int r = 0; r < 4; ++r)
                op0[(size_t)r * OW + j * 16] = acc[j][r] + b;
        }
    } else {
#pragma unroll
        for (int j = 0; j < NJ; ++j) {
            int oc = ocol + j * 16;
            if (oc < OW) {
#pragma unroll
                for (int r = 0; r < 4; ++r) {
                    int orow = orow0 + r;
                    if (orow < OH)
                        Out[(size_t)orow * OW + oc] = acc[j][r] + b;
                }
            }
        }
    }
}

extern "C" void kernel_launch(void* const* d_in, const int* in_sizes, int n_in,
                              void* d_out, int out_size, void* d_ws, size_t ws_size,
                              hipStream_t stream)
{
    const float* X    = (const float*)d_in[0];
    const float* Wt   = (const float*)d_in[1];
    const float* Bias = (const float*)d_in[2];
    float* Out        = (float*)d_out;
    ushort* Bw        = (ushort*)d_ws;        // 15*64*8 ushort = 15360 B

    hipLaunchKernelGGL(build_wfrags, dim3((KH * 64 + 255) / 256), dim3(256), 0, stream,
                       Wt, Bw);

    dim3 grid((OW + BN - 1) / BN,    // 32
              (OH + BM - 1) / BM);   // 64
    dim3 block(256);
    hipLaunchKernelGGL(conv2d_mfma_bf16, grid, block, 0, stream, X, Bw, Bias, Out);
}